// Round 1
// baseline (145.471 us; speedup 1.0000x reference)
//
#include <hip/hip_runtime.h>
#include <hip/hip_bf16.h>

// ContrastiveLoss: B=8192 samples, D=128 dims, 100 classes.
// loss_i = -log( max(sum_{j!=i, lab_j==lab_i} e^{s_ij}, 1e-8)
//              / max(sum_{j!=i}              e^{s_ij}, 1e-8) ),  out = mean_i loss_i
// s_ij = clip( (f_i/||f_i||)·(f_j/||f_j||) / 0.07, -10, 10 )
//
// Trick: store fb = f_hat * sqrt(log2e/0.07) in bf16; then the MFMA dot gives
// s_ij/0.07*log2e directly -> clamp at +-10*log2e and exp2 (one v_exp_f32).
// Diagonal excluded exactly via wave-uniform tile check (bf16 self-dot != 1
// exactly, so subtracting exp(10) as a constant would be wrong by ~4%).

using short8  = __attribute__((ext_vector_type(8))) short;   // 8 bf16 = 4 VGPRs
using floatx4 = __attribute__((ext_vector_type(4))) float;

constexpr int   Bn = 8192;
constexpr int   Dk = 128;
constexpr float PRESCALE = 4.5398160f;     // sqrt(log2(e)/0.07)
constexpr float CLAMP    = 14.4269504f;    // 10*log2(e)
constexpr float LN2      = 0.69314718056f;

// ---- kernel 1: row L2-normalize, scale, cast to bf16 --------------------
__global__ __launch_bounds__(256) void normalize_k(
    const float* __restrict__ feat, unsigned short* __restrict__ fb) {
  const int row  = blockIdx.x * 4 + (threadIdx.x >> 6);
  const int lane = threadIdx.x & 63;
  const float2 v = ((const float2*)(feat + (size_t)row * Dk))[lane];
  float s = v.x * v.x + v.y * v.y;
#pragma unroll
  for (int m = 1; m < 64; m <<= 1) s += __shfl_xor(s, m);
  const float inv = PRESCALE / fmaxf(sqrtf(s), 1e-8f);
  __hip_bfloat16 b0 = __float2bfloat16(v.x * inv);
  __hip_bfloat16 b1 = __float2bfloat16(v.y * inv);
  ushort2 o;
  o.x = __builtin_bit_cast(unsigned short, b0);
  o.y = __builtin_bit_cast(unsigned short, b1);
  ((ushort2*)(fb + (size_t)row * Dk))[lane] = o;
}

// ---- kernel 2: tiled F*F^T with fused exp + masked row-sum --------------
// grid: (32 j-slices, 64 i-blocks). Block = 256 thr = 4 waves.
// Each wave: 32 rows (two 16-row MFMA tiles, A frags register-resident),
// iterates 16 col-tiles of 16 over its 256-col slice. B frags direct from L2.
__global__ __launch_bounds__(256, 4) void simloss_k(
    const unsigned short* __restrict__ fb, const int* __restrict__ labels,
    float* __restrict__ rowpos, float* __restrict__ rowneg) {
  const int lane  = threadIdx.x & 63;
  const int wave  = threadIdx.x >> 6;
  const int quad  = lane >> 4;
  const int lr    = lane & 15;
  const int ibase = blockIdx.y * 128 + wave * 32;   // rows [ibase, ibase+32)
  const int jbase = blockIdx.x * 256;               // cols [jbase, jbase+256)

  // A fragments: lane holds fb[ibase + t*16 + lr][quad*8 + kk*32 .. +8]
  short8 afrag[2][4];
#pragma unroll
  for (int t = 0; t < 2; ++t) {
    const short* ap = (const short*)fb + (size_t)(ibase + t * 16 + lr) * Dk + quad * 8;
#pragma unroll
    for (int kk = 0; kk < 4; ++kk)
      afrag[t][kk] = *(const short8*)(ap + kk * 32);
  }
  // labels of this lane's accumulator rows: row_in_tile = quad*4 + r
  int li[2][4];
#pragma unroll
  for (int t = 0; t < 2; ++t)
#pragma unroll
    for (int r = 0; r < 4; ++r)
      li[t][r] = labels[ibase + t * 16 + quad * 4 + r];

  float pos[2][4] = {{0.f,0.f,0.f,0.f},{0.f,0.f,0.f,0.f}};
  float neg[2][4] = {{0.f,0.f,0.f,0.f},{0.f,0.f,0.f,0.f}};

  for (int jt = 0; jt < 16; ++jt) {
    const int j0   = jbase + jt * 16;
    const int brow = j0 + lr;
    const short* bp = (const short*)fb + (size_t)brow * Dk + quad * 8;
    short8 bfrag[4];
#pragma unroll
    for (int kk = 0; kk < 4; ++kk) bfrag[kk] = *(const short8*)(bp + kk * 32);
    const int lj = labels[brow];    // label of this lane's column

    floatx4 acc0 = {0.f,0.f,0.f,0.f}, acc1 = {0.f,0.f,0.f,0.f};
#pragma unroll
    for (int kk = 0; kk < 4; ++kk) {
      acc0 = __builtin_amdgcn_mfma_f32_16x16x32_bf16(afrag[0][kk], bfrag[kk], acc0, 0, 0, 0);
      acc1 = __builtin_amdgcn_mfma_f32_16x16x32_bf16(afrag[1][kk], bfrag[kk], acc1, 0, 0, 0);
    }
    // epilogue: C/D layout col = lane&15, row = quad*4 + r  [m89/m91]
#pragma unroll
    for (int t = 0; t < 2; ++t) {
      const floatx4 acc = t ? acc1 : acc0;
      const bool dtile = (j0 == ibase + t * 16);  // wave-uniform: tile on diagonal
#pragma unroll
      for (int r = 0; r < 4; ++r) {
        float x = fminf(fmaxf(acc[r], -CLAMP), CLAMP);
        float e = __builtin_amdgcn_exp2f(x);
        if (dtile && (quad * 4 + r) == lr) e = 0.f;  // exclude i==j exactly
        neg[t][r] += e;
        pos[t][r] += (li[t][r] == lj) ? e : 0.f;
      }
    }
  }

  // reduce across the 16 lanes of a col-group (xor 1,2,4,8 stays in group)
#pragma unroll
  for (int t = 0; t < 2; ++t)
#pragma unroll
    for (int r = 0; r < 4; ++r) {
      float p = pos[t][r], n = neg[t][r];
#pragma unroll
      for (int m = 1; m < 16; m <<= 1) {
        p += __shfl_xor(p, m);
        n += __shfl_xor(n, m);
      }
      if (lr == 0) {
        const int row = ibase + t * 16 + quad * 4 + r;
        atomicAdd(&rowpos[row], p);
        atomicAdd(&rowneg[row], n);
      }
    }
}

// ---- kernel 3: per-row loss + mean ---------------------------------------
__global__ __launch_bounds__(256) void finalize_k(
    const float* __restrict__ rowpos, const float* __restrict__ rowneg,
    float* __restrict__ out) {
  const int i = blockIdx.x * 256 + threadIdx.x;
  const float p = fmaxf(rowpos[i], 1e-8f);
  const float n = fmaxf(rowneg[i], 1e-8f);
  // -log(p/n) = ln2 * (log2(n) - log2(p))
  float loss = LN2 * (__builtin_amdgcn_logf(n) - __builtin_amdgcn_logf(p));
#pragma unroll
  for (int m = 1; m < 64; m <<= 1) loss += __shfl_xor(loss, m);
  __shared__ float partial[4];
  const int lane = threadIdx.x & 63, w = threadIdx.x >> 6;
  if (lane == 0) partial[w] = loss;
  __syncthreads();
  if (threadIdx.x == 0) {
    const float s = partial[0] + partial[1] + partial[2] + partial[3];
    atomicAdd(out, s * (1.0f / (float)Bn));
  }
}

extern "C" void kernel_launch(void* const* d_in, const int* in_sizes, int n_in,
                              void* d_out, int out_size, void* d_ws, size_t ws_size,
                              hipStream_t stream) {
  const float* feat   = (const float*)d_in[0];
  const int*   labels = (const int*)d_in[1];
  float* out = (float*)d_out;

  // ws layout: [0, 2MB) bf16 fb[8192][128]; then rowpos[8192], rowneg[8192]
  unsigned short* fb = (unsigned short*)d_ws;
  float* rowpos = (float*)((char*)d_ws + (size_t)Bn * Dk * sizeof(unsigned short));
  float* rowneg = rowpos + Bn;

  hipMemsetAsync(rowpos, 0, (size_t)Bn * 2 * sizeof(float), stream);
  hipMemsetAsync(out, 0, sizeof(float), stream);

  normalize_k<<<Bn / 4, 256, 0, stream>>>(feat, fb);
  dim3 grid(32, 64);  // x = j-slice, y = i-block
  simloss_k<<<grid, 256, 0, stream>>>(fb, labels, rowpos, rowneg);
  finalize_k<<<Bn / 256, 256, 0, stream>>>(rowpos, rowneg, out);
}